// Round 2
// baseline (231.824 us; speedup 1.0000x reference)
//
#include <hip/hip_runtime.h>
#include <hip/hip_fp16.h>

// MMD loss: N=4096, D=512, ns=8192. result = (1/n^2) * sum_ij sigma_i sigma_j K(L2_ij)
// bandwidth = [2*ns*sum(sq) - 2*||colsum||^2] / (ns^2-ns) / 4; scales bw*2^s, s=0..4
// exp2 chain: K_s = exp2(c0*L2 / 2^s) = sqrt(K_{s-1})

#define NS 8192
#define D_DIM 512
#define NTILE 64   // NS / 128
#define NBLK 2080  // NTILE*(NTILE+1)/2

typedef _Float16 f16x8 __attribute__((ext_vector_type(8)));
typedef float f32x4 __attribute__((ext_vector_type(4)));

// ---------------- fused prep: convert + row-sq + colsum ----------------
__global__ __launch_bounds__(256) void prep(const float* __restrict__ src,
                                            const float* __restrict__ tgt,
                                            __half* __restrict__ Th,
                                            float* __restrict__ sq,
                                            float* __restrict__ colsum) {
    __shared__ float lcs[4][D_DIM];
    int tid = threadIdx.x, w = tid >> 6, l = tid & 63;
    int r0 = blockIdx.x * 16 + w * 4;          // 512 blocks * 16 rows, 4 rows/wave
    float cs[8];
#pragma unroll
    for (int j = 0; j < 8; ++j) cs[j] = 0.f;

#pragma unroll
    for (int rr = 0; rr < 4; ++rr) {
        int r = r0 + rr;
        const float* rowp = (r < 4096) ? (src + (size_t)r * D_DIM)
                                       : (tgt + (size_t)(r - 4096) * D_DIM);
        float4 v0 = *reinterpret_cast<const float4*>(rowp + l * 8);
        float4 v1 = *reinterpret_cast<const float4*>(rowp + l * 8 + 4);
        float f[8] = {v0.x, v0.y, v0.z, v0.w, v1.x, v1.y, v1.z, v1.w};
        __half h[8];
        float s = 0.f;
#pragma unroll
        for (int j = 0; j < 8; ++j) {
            h[j] = __float2half(f[j]);
            float fj = __half2float(h[j]);
            s += fj * fj;
            cs[j] += fj;
        }
        *reinterpret_cast<int4*>(Th + (size_t)r * D_DIM + l * 8) =
            *reinterpret_cast<const int4*>(h);
#pragma unroll
        for (int off = 32; off; off >>= 1) s += __shfl_xor(s, off, 64);
        if (l == 0) sq[r] = s;
    }
#pragma unroll
    for (int j = 0; j < 8; ++j) lcs[w][l * 8 + j] = cs[j];
    __syncthreads();
#pragma unroll
    for (int j = 0; j < 2; ++j) {
        int c = tid * 2 + j;
        float v = (lcs[0][c] + lcs[1][c]) + (lcs[2][c] + lcs[3][c]);
        atomicAdd(&colsum[c], v);
    }
}

// ---------------- bandwidth scalar + zero accumulator ----------------
__global__ void compute_bw(const float* __restrict__ sq, const float* __restrict__ colsum,
                           float* __restrict__ cs, double* __restrict__ acc) {
    __shared__ float red[256];
    int t = threadIdx.x;
    float s = 0.f;
    for (int i = t; i < NS; i += 256) s += sq[i];
    float c = 0.f;
    for (int i = t; i < D_DIM; i += 256) { float v = colsum[i]; c += v * v; }
    red[t] = s; __syncthreads();
    for (int off = 128; off; off >>= 1) { if (t < off) red[t] += red[t + off]; __syncthreads(); }
    float S = red[0]; __syncthreads();
    red[t] = c; __syncthreads();
    for (int off = 128; off; off >>= 1) { if (t < off) red[t] += red[t + off]; __syncthreads(); }
    if (t == 0) {
        float C = red[0];
        double sumL2 = 2.0 * (double)NS * (double)S - 2.0 * (double)C;
        double bw = sumL2 / ((double)NS * NS - (double)NS) / 4.0;  // / kernel_mul^(num//2)
        cs[0] = (float)(-1.4426950408889634 / bw);
        *acc = 0.0;
    }
}

// ---------------- main: triangular tiled gram + fused kernel-sum ----------------
__global__ __launch_bounds__(256, 4) void mmd_main(const __half* __restrict__ Th,
                                                   const float* __restrict__ sq,
                                                   const float* __restrict__ cs,
                                                   double* __restrict__ acc_out) {
    __shared__ __half Ah[128 * 64];
    __shared__ __half Bh[128 * 64];

    // XCD swizzle (2080 = 8*260, bijective) then upper-triangle decode
    int b = blockIdx.x;
    b = (b & 7) * (NBLK / 8) + (b >> 3);
    int ti = 0, rem = b;
    while (rem >= NTILE - ti) { rem -= NTILE - ti; ++ti; }
    int tj = ti + rem;
    int ibase = ti * 128, jbase = tj * 128;
    float wgt = ((ti == tj) ? 1.f : 2.f) * (((ti < 32) == (tj < 32)) ? 1.f : -1.f);

    int tid = threadIdx.x;
    int wid = tid >> 6, lane = tid & 63;
    int wm = wid >> 1, wn = wid & 1;     // wave -> 64x64 quadrant
    int cl = lane >> 4;                  // k-chunk index 0..3

    f32x4 acc[4][4];
#pragma unroll
    for (int m = 0; m < 4; ++m)
#pragma unroll
        for (int n = 0; n < 4; ++n) acc[m][n] = f32x4{0.f, 0.f, 0.f, 0.f};

    for (int k0 = 0; k0 < D_DIM; k0 += 64) {
        // stage A and B 128x64 tiles; global source pre-swizzled chunk^(row&7)
#pragma unroll
        for (int it = 0; it < 4; ++it) {
            int h16 = tid + it * 256;            // 16B unit within tile
            int row = h16 >> 3, ch = h16 & 7;
            int scol = ((ch ^ (row & 7)) * 8);
            __builtin_amdgcn_global_load_lds(
                (const __attribute__((address_space(1))) unsigned int*)(Th + (size_t)(ibase + row) * D_DIM + k0 + scol),
                (__attribute__((address_space(3))) unsigned int*)(Ah + h16 * 8), 16, 0, 0);
            __builtin_amdgcn_global_load_lds(
                (const __attribute__((address_space(1))) unsigned int*)(Th + (size_t)(jbase + row) * D_DIM + k0 + scol),
                (__attribute__((address_space(3))) unsigned int*)(Bh + h16 * 8), 16, 0, 0);
        }
        __syncthreads();

#pragma unroll
        for (int ks = 0; ks < 2; ++ks) {
            f16x8 afr[4], bfr[4];
#pragma unroll
            for (int m = 0; m < 4; ++m) {
                int ra = wm * 64 + m * 16 + (lane & 15);
                int pc = (ks * 4 + cl) ^ (ra & 7);
                afr[m] = *reinterpret_cast<const f16x8*>(&Ah[ra * 64 + pc * 8]);
            }
#pragma unroll
            for (int n = 0; n < 4; ++n) {
                int rb = wn * 64 + n * 16 + (lane & 15);
                int pc = (ks * 4 + cl) ^ (rb & 7);
                bfr[n] = *reinterpret_cast<const f16x8*>(&Bh[rb * 64 + pc * 8]);
            }
#pragma unroll
            for (int m = 0; m < 4; ++m)
#pragma unroll
                for (int n = 0; n < 4; ++n)
                    acc[m][n] = __builtin_amdgcn_mfma_f32_16x16x32_f16(afr[m], bfr[n], acc[m][n], 0, 0, 0);
        }
        __syncthreads();
    }

    // epilogue: x0 = c0*L2 ; K_s via sqrt chain ; signed sum
    float c0 = cs[0];
    float m2c0 = -2.f * c0;
    float sci[16], scj[4];
#pragma unroll
    for (int m = 0; m < 4; ++m)
#pragma unroll
        for (int r = 0; r < 4; ++r)
            sci[m * 4 + r] = sq[ibase + wm * 64 + m * 16 + (lane >> 4) * 4 + r] * c0;
#pragma unroll
    for (int n = 0; n < 4; ++n)
        scj[n] = sq[jbase + wn * 64 + n * 16 + (lane & 15)] * c0;

    float a0 = 0.f, a1 = 0.f, a2 = 0.f, a3 = 0.f, a4 = 0.f;
#pragma unroll
    for (int m = 0; m < 4; ++m)
#pragma unroll
        for (int n = 0; n < 4; ++n)
#pragma unroll
            for (int r = 0; r < 4; ++r) {
                float x0 = fmaf(acc[m][n][r], m2c0, sci[m * 4 + r] + scj[n]);
                float e0 = __builtin_amdgcn_exp2f(x0);
                float e1 = __builtin_amdgcn_sqrtf(e0);
                float e2 = __builtin_amdgcn_sqrtf(e1);
                float e3 = __builtin_amdgcn_sqrtf(e2);
                float e4 = __builtin_amdgcn_sqrtf(e3);
                a0 += e0; a1 += e1; a2 += e2; a3 += e3; a4 += e4;
            }
    float ksum = ((a0 + a1) + (a2 + a3)) + a4;
#pragma unroll
    for (int off = 32; off; off >>= 1) ksum += __shfl_xor(ksum, off, 64);
    if (lane == 0) atomicAdd(acc_out, (double)(ksum * wgt));
}

__global__ void finalize(const double* __restrict__ acc, float* __restrict__ out) {
    out[0] = (float)(*acc * (1.0 / (4096.0 * 4096.0)));
}

extern "C" void kernel_launch(void* const* d_in, const int* in_sizes, int n_in,
                              void* d_out, int out_size, void* d_ws, size_t ws_size,
                              hipStream_t stream) {
    (void)in_sizes; (void)n_in; (void)out_size; (void)ws_size;
    const float* src = (const float*)d_in[0];
    const float* tgt = (const float*)d_in[1];
    char* ws = (char*)d_ws;
    __half* Th    = (__half*)ws;                       // 8192*512*2 = 8,388,608 B
    float* sq     = (float*)(ws + 8388608);            // 32 KB
    float* colsum = (float*)(ws + 8421376);            // 2 KB
    float* cs     = (float*)(ws + 8423424);            // 8 B
    double* acc   = (double*)(ws + 8423432);           // 8 B, 8-aligned
    float* out    = (float*)d_out;

    hipMemsetAsync(colsum, 0, D_DIM * sizeof(float), stream);
    hipLaunchKernelGGL(prep, dim3(512), dim3(256), 0, stream, src, tgt, Th, sq, colsum);
    hipLaunchKernelGGL(compute_bw, dim3(1), dim3(256), 0, stream, sq, colsum, cs, acc);
    hipLaunchKernelGGL(mmd_main, dim3(NBLK), dim3(256), 0, stream, Th, sq, cs, acc);
    hipLaunchKernelGGL(finalize, dim3(1), dim3(1), 0, stream, acc, out);
}

// Round 3
// 161.087 us; speedup vs baseline: 1.4391x; 1.4391x over previous
//
#include <hip/hip_runtime.h>
#include <hip/hip_fp16.h>

// MMD loss: N=4096, D=512, ns=8192. result = (1/n^2) * sum_ij sigma_i sigma_j K(L2_ij)
// bandwidth = [2*ns*sum(sq) - 2*||colsum||^2] / (ns^2-ns) / 4; scales bw*2^s, s=0..4
// exp2 chain: K_s = exp2(c0*L2 / 2^s) = sqrt(K_{s-1})

#define NS 8192
#define D_DIM 512
#define NTILE 64   // NS / 128
#define NBLK 2080  // NTILE*(NTILE+1)/2

typedef _Float16 f16x8 __attribute__((ext_vector_type(8)));
typedef float f32x4 __attribute__((ext_vector_type(4)));

// ---------------- fused prep: convert + row-sq + colsum + sum(sq) ----------------
__global__ __launch_bounds__(256) void prep(const float* __restrict__ src,
                                            const float* __restrict__ tgt,
                                            __half* __restrict__ Th,
                                            float* __restrict__ sq,
                                            float* __restrict__ colsum,
                                            float* __restrict__ Sacc) {
    __shared__ float lcs[4][D_DIM];
    __shared__ float wsq[4];
    int tid = threadIdx.x, w = tid >> 6, l = tid & 63;
    int r0 = blockIdx.x * 16 + w * 4;          // 512 blocks * 16 rows, 4 rows/wave
    float cs[8];
#pragma unroll
    for (int j = 0; j < 8; ++j) cs[j] = 0.f;
    float ws = 0.f;

#pragma unroll
    for (int rr = 0; rr < 4; ++rr) {
        int r = r0 + rr;
        const float* rowp = (r < 4096) ? (src + (size_t)r * D_DIM)
                                       : (tgt + (size_t)(r - 4096) * D_DIM);
        float4 v0 = *reinterpret_cast<const float4*>(rowp + l * 8);
        float4 v1 = *reinterpret_cast<const float4*>(rowp + l * 8 + 4);
        float f[8] = {v0.x, v0.y, v0.z, v0.w, v1.x, v1.y, v1.z, v1.w};
        __half h[8];
        float s = 0.f;
#pragma unroll
        for (int j = 0; j < 8; ++j) {
            h[j] = __float2half(f[j]);
            float fj = __half2float(h[j]);
            s += fj * fj;
            cs[j] += fj;
        }
        *reinterpret_cast<int4*>(Th + (size_t)r * D_DIM + l * 8) =
            *reinterpret_cast<const int4*>(h);
#pragma unroll
        for (int off = 32; off; off >>= 1) s += __shfl_xor(s, off, 64);
        if (l == 0) { sq[r] = s; ws += s; }
    }
    if (l == 0) wsq[w] = ws;
#pragma unroll
    for (int j = 0; j < 8; ++j) lcs[w][l * 8 + j] = cs[j];
    __syncthreads();
#pragma unroll
    for (int j = 0; j < 2; ++j) {
        int c = tid * 2 + j;
        float v = (lcs[0][c] + lcs[1][c]) + (lcs[2][c] + lcs[3][c]);
        atomicAdd(&colsum[c], v);
    }
    if (tid == 0) atomicAdd(Sacc, (wsq[0] + wsq[1]) + (wsq[2] + wsq[3]));
}

// ---------------- bandwidth scalar ----------------
__global__ void compute_bw(const float* __restrict__ colsum, const float* __restrict__ Sacc,
                           float* __restrict__ cs) {
    __shared__ float red[256];
    int t = threadIdx.x;
    float c = 0.f;
    for (int i = t; i < D_DIM; i += 256) { float v = colsum[i]; c += v * v; }
    red[t] = c; __syncthreads();
    for (int off = 128; off; off >>= 1) { if (t < off) red[t] += red[t + off]; __syncthreads(); }
    if (t == 0) {
        double C = red[0];
        double S = (double)Sacc[0];
        double sumL2 = 2.0 * (double)NS * S - 2.0 * C;
        double bw = sumL2 / ((double)NS * NS - (double)NS) / 4.0;  // / kernel_mul^(num//2)
        cs[0] = (float)(-1.4426950408889634 / bw);
    }
}

// ---------------- main: triangular tiled gram + fused kernel-sum ----------------
__global__ __launch_bounds__(256, 2) void mmd_main(const __half* __restrict__ Th,
                                                   const float* __restrict__ sq,
                                                   const float* __restrict__ cs,
                                                   float* __restrict__ partials) {
    __shared__ __half Ah[2][128 * 64];
    __shared__ __half Bh[2][128 * 64];
    __shared__ float wred[4];

    // XCD swizzle (2080 = 8*260, bijective) then upper-triangle decode
    int borig = blockIdx.x;
    int b = (borig & 7) * (NBLK / 8) + (borig >> 3);
    int ti = 0, rem = b;
    while (rem >= NTILE - ti) { rem -= NTILE - ti; ++ti; }
    int tj = ti + rem;
    int ibase = ti * 128, jbase = tj * 128;
    float wgt = ((ti == tj) ? 1.f : 2.f) * (((ti < 32) == (tj < 32)) ? 1.f : -1.f);

    int tid = threadIdx.x;
    int wid = tid >> 6, lane = tid & 63;
    int wm = wid >> 1, wn = wid & 1;     // wave -> 64x64 quadrant
    int cl = lane >> 4;                  // k-chunk index 0..3

    f32x4 acc[4][4];
#pragma unroll
    for (int m = 0; m < 4; ++m)
#pragma unroll
        for (int n = 0; n < 4; ++n) acc[m][n] = f32x4{0.f, 0.f, 0.f, 0.f};

    // stage tile (global source pre-swizzled chunk^(row&7), LDS linear)
    auto STAGE = [&](int buf, int k0) {
#pragma unroll
        for (int it = 0; it < 4; ++it) {
            int h16 = tid + it * 256;            // 16B unit within 128x64 tile
            int row = h16 >> 3, ch = h16 & 7;
            int scol = ((ch ^ (row & 7)) * 8);
            __builtin_amdgcn_global_load_lds(
                (const __attribute__((address_space(1))) unsigned int*)(Th + (size_t)(ibase + row) * D_DIM + k0 + scol),
                (__attribute__((address_space(3))) unsigned int*)(&Ah[buf][h16 * 8]), 16, 0, 0);
            __builtin_amdgcn_global_load_lds(
                (const __attribute__((address_space(1))) unsigned int*)(Th + (size_t)(jbase + row) * D_DIM + k0 + scol),
                (__attribute__((address_space(3))) unsigned int*)(&Bh[buf][h16 * 8]), 16, 0, 0);
        }
    };

    auto COMPUTE = [&](int buf) {
#pragma unroll
        for (int ks = 0; ks < 2; ++ks) {
            f16x8 afr[4], bfr[4];
#pragma unroll
            for (int m = 0; m < 4; ++m) {
                int ra = wm * 64 + m * 16 + (lane & 15);
                int pc = (ks * 4 + cl) ^ (ra & 7);
                afr[m] = *reinterpret_cast<const f16x8*>(&Ah[buf][ra * 64 + pc * 8]);
            }
#pragma unroll
            for (int n = 0; n < 4; ++n) {
                int rb = wn * 64 + n * 16 + (lane & 15);
                int pc = (ks * 4 + cl) ^ (rb & 7);
                bfr[n] = *reinterpret_cast<const f16x8*>(&Bh[buf][rb * 64 + pc * 8]);
            }
#pragma unroll
            for (int m = 0; m < 4; ++m)
#pragma unroll
                for (int n = 0; n < 4; ++n)
                    acc[m][n] = __builtin_amdgcn_mfma_f32_16x16x32_f16(afr[m], bfr[n], acc[m][n], 0, 0, 0);
        }
    };

    // 2-phase pipeline: issue next-tile stage BEFORE current-tile compute;
    // one barrier per tile (its implicit vmcnt/lgkmcnt drain = correctness).
    STAGE(0, 0);
    __syncthreads();
    int buf = 0;
#pragma unroll
    for (int t = 0; t < 7; ++t) {
        STAGE(buf ^ 1, (t + 1) * 64);
        COMPUTE(buf);
        __syncthreads();
        buf ^= 1;
    }
    COMPUTE(buf);

    // epilogue: x0 = c0*L2 ; K_s via sqrt chain ; signed sum
    float c0 = cs[0];
    float m2c0 = -2.f * c0;
    float sci[16], scj[4];
#pragma unroll
    for (int m = 0; m < 4; ++m)
#pragma unroll
        for (int r = 0; r < 4; ++r)
            sci[m * 4 + r] = sq[ibase + wm * 64 + m * 16 + (lane >> 4) * 4 + r] * c0;
#pragma unroll
    for (int n = 0; n < 4; ++n)
        scj[n] = sq[jbase + wn * 64 + n * 16 + (lane & 15)] * c0;

    float a0 = 0.f, a1 = 0.f, a2 = 0.f, a3 = 0.f, a4 = 0.f;
#pragma unroll
    for (int m = 0; m < 4; ++m)
#pragma unroll
        for (int n = 0; n < 4; ++n)
#pragma unroll
            for (int r = 0; r < 4; ++r) {
                float x0 = fmaf(acc[m][n][r], m2c0, sci[m * 4 + r] + scj[n]);
                float e0 = __builtin_amdgcn_exp2f(x0);
                float e1 = __builtin_amdgcn_sqrtf(e0);
                float e2 = __builtin_amdgcn_sqrtf(e1);
                float e3 = __builtin_amdgcn_sqrtf(e2);
                float e4 = __builtin_amdgcn_sqrtf(e3);
                a0 += e0; a1 += e1; a2 += e2; a3 += e3; a4 += e4;
            }
    float ksum = ((a0 + a1) + (a2 + a3)) + a4;
#pragma unroll
    for (int off = 32; off; off >>= 1) ksum += __shfl_xor(ksum, off, 64);
    if (lane == 0) wred[wid] = ksum;
    __syncthreads();
    if (tid == 0)
        partials[borig] = ((wred[0] + wred[1]) + (wred[2] + wred[3])) * wgt;
}

__global__ void finalize(const float* __restrict__ partials, float* __restrict__ out) {
    __shared__ double red[256];
    int t = threadIdx.x;
    double s = 0.0;
    for (int i = t; i < NBLK; i += 256) s += (double)partials[i];
    red[t] = s; __syncthreads();
    for (int off = 128; off; off >>= 1) { if (t < off) red[t] += red[t + off]; __syncthreads(); }
    if (t == 0) out[0] = (float)(red[0] * (1.0 / (4096.0 * 4096.0)));
}

extern "C" void kernel_launch(void* const* d_in, const int* in_sizes, int n_in,
                              void* d_out, int out_size, void* d_ws, size_t ws_size,
                              hipStream_t stream) {
    (void)in_sizes; (void)n_in; (void)out_size; (void)ws_size;
    const float* src = (const float*)d_in[0];
    const float* tgt = (const float*)d_in[1];
    char* ws = (char*)d_ws;
    __half* Th      = (__half*)ws;                     // 8192*512*2 = 8,388,608 B
    float* sq       = (float*)(ws + 8388608);          // 32 KB
    float* colsum   = (float*)(ws + 8421376);          // 2048 B
    float* Sacc     = (float*)(ws + 8423424);          // 4 B
    float* cs       = (float*)(ws + 8423428);          // 4 B
    float* partials = (float*)(ws + 8423432);          // 2080*4 B
    float* out      = (float*)d_out;

    hipMemsetAsync(colsum, 0, 2052, stream);           // colsum + Sacc
    hipLaunchKernelGGL(prep, dim3(512), dim3(256), 0, stream, src, tgt, Th, sq, colsum, Sacc);
    hipLaunchKernelGGL(compute_bw, dim3(1), dim3(256), 0, stream, colsum, Sacc, cs);
    hipLaunchKernelGGL(mmd_main, dim3(NBLK), dim3(256), 0, stream, Th, sq, cs, partials);
    hipLaunchKernelGGL(finalize, dim3(1), dim3(256), 0, stream, partials, out);
}